// Round 1
// baseline (283.097 us; speedup 1.0000x reference)
//
#include <hip/hip_runtime.h>

typedef float f32x4 __attribute__((ext_vector_type(4)));

#define P1 254   // pooled size after C1+S2
#define P2 125   // pooled size after C3+S4
#define C5_K 250000           // 16*125*125
#define C5_K4 62500           // in float4
#define C5_CHUNK_F4 3125      // 20 chunks per row -> grid (20,120) = 2400 blocks
#define F6_OUT 98304

#define F6_RPB 96             // rows per block (divides 98304 -> 1024 blocks)
#define F6_STRIDE 124         // LDS row stride (pad +4 floats, bank-conflict free)
#define F6_NBLK (F6_OUT / F6_RPB)       // 1024
#define F6_PANEL_F4 (F6_RPB * 120 / 4)  // 2880 float4 per W6 panel

// ---- ws layout (floats) ----
#define WS_H2 0        // 6*254*254 = 387096
#define WS_H4 400000   // 16*125*125 = 250000
#define WS_C5 650000   // 120

__device__ __forceinline__ float4 nt_load4(const float4* p) {
    f32x4 v = __builtin_nontemporal_load((const f32x4*)p);
    return make_float4(v.x, v.y, v.z, v.w);
}

// C1 conv 5x5 (1->6) + ReLU + 2x2 avgpool, fused. One thread per pooled output.
// Block 0 also seeds the c5 accumulator (b5) and the output accumulator (b7).
__global__ __launch_bounds__(256) void c1_s2_kernel(const float* __restrict__ x,
        const float* __restrict__ W1, const float* __restrict__ b1,
        float* __restrict__ h2,
        const float* __restrict__ b5, const float* __restrict__ b7,
        float* __restrict__ c5acc, float* __restrict__ out) {
    if (blockIdx.x == 0) {
        int t = threadIdx.x;
        if (t < 120) c5acc[t] = b5[t];
        if (t >= 128 && t < 182) out[t - 128] = b7[t - 128];
    }
    int t = blockIdx.x * 256 + threadIdx.x;
    const int total = 6 * P1 * P1;
    if (t >= total) return;
    int c  = t / (P1 * P1);
    int r  = t % (P1 * P1);
    int y  = r / P1, x0 = r % P1;

    float w[25];
    #pragma unroll
    for (int k = 0; k < 25; ++k) w[k] = W1[c * 25 + k];

    float p[6][6];
    const float2* xin2 = (const float2*)(x + (2 * y) * 512 + 2 * x0);  // 8B-aligned
    #pragma unroll
    for (int i = 0; i < 6; ++i) {
        float2 a0 = xin2[i * 256 + 0];
        float2 a1 = xin2[i * 256 + 1];
        float2 a2 = xin2[i * 256 + 2];
        p[i][0] = a0.x; p[i][1] = a0.y; p[i][2] = a1.x;
        p[i][3] = a1.y; p[i][4] = a2.x; p[i][5] = a2.y;
    }

    float bias = b1[c];
    float s = 0.f;
    #pragma unroll
    for (int dy = 0; dy < 2; ++dy)
        #pragma unroll
        for (int dx = 0; dx < 2; ++dx) {
            float a = bias;
            #pragma unroll
            for (int kh = 0; kh < 5; ++kh)
                #pragma unroll
                for (int kw = 0; kw < 5; ++kw)
                    a = fmaf(p[dy + kh][dx + kw], w[kh * 5 + kw], a);
            s += fmaxf(a, 0.f);
        }
    h2[t] = 0.25f * s;
}

// C3 sparse-connected conv 5x5 (6->16) + ReLU + 2x2 avgpool, fused.
__global__ __launch_bounds__(256) void c3_s4_kernel(const float* __restrict__ h2,
        const float* __restrict__ W3, const float* __restrict__ b3,
        float* __restrict__ h4) {
    const unsigned char MASK[16] = {7,14,28,56,49,35,15,30,60,57,51,39,27,54,45,63};
    int t = blockIdx.x * 256 + threadIdx.x;
    const int total = 16 * P2 * P2;
    if (t >= total) return;
    int o  = t / (P2 * P2);
    int r  = t % (P2 * P2);
    int y  = r / P2, x0 = r % P2;

    float a00, a01, a10, a11;
    a00 = a01 = a10 = a11 = b3[o];
    unsigned m = MASK[o];

    for (int i = 0; i < 6; ++i) {
        if (!((m >> i) & 1)) continue;
        const float2* hp2 = (const float2*)(h2 + i * P1 * P1 + (2 * y) * P1 + 2 * x0);
        const float* wp = W3 + (o * 6 + i) * 25;
        float w[25];
        #pragma unroll
        for (int k = 0; k < 25; ++k) w[k] = wp[k];
        float p[6][6];
        #pragma unroll
        for (int ii = 0; ii < 6; ++ii) {
            float2 a0 = hp2[ii * 127 + 0];
            float2 a1 = hp2[ii * 127 + 1];
            float2 a2 = hp2[ii * 127 + 2];
            p[ii][0] = a0.x; p[ii][1] = a0.y; p[ii][2] = a1.x;
            p[ii][3] = a1.y; p[ii][4] = a2.x; p[ii][5] = a2.y;
        }
        #pragma unroll
        for (int kh = 0; kh < 5; ++kh)
            #pragma unroll
            for (int kw = 0; kw < 5; ++kw) {
                float wv = w[kh * 5 + kw];
                a00 = fmaf(p[kh][kw],         wv, a00);
                a01 = fmaf(p[kh][kw + 1],     wv, a01);
                a10 = fmaf(p[kh + 1][kw],     wv, a10);
                a11 = fmaf(p[kh + 1][kw + 1], wv, a11);
            }
    }
    h4[t] = 0.25f * (fmaxf(a00, 0.f) + fmaxf(a01, 0.f) + fmaxf(a10, 0.f) + fmaxf(a11, 0.f));
}

__device__ __forceinline__ float block_reduce_256(float v) {
    #pragma unroll
    for (int off = 32; off > 0; off >>= 1) v += __shfl_down(v, off, 64);
    __shared__ float s[4];
    int lane = threadIdx.x & 63, wv = threadIdx.x >> 6;
    if (lane == 0) s[wv] = v;
    __syncthreads();
    return s[0] + s[1] + s[2] + s[3];
}

// C5: 120 dot-products of length 250000. Split-K, compile-time trip count:
// 3125 f4/chunk = 12*256 + 53 -> 6 unrolled x2 iterations + predicated tail.
// Dual accumulators + paired nt loads keep the 120 MB W5 stream deep in flight.
__global__ __launch_bounds__(256) void c5_kernel(const float* __restrict__ h4,
        const float* __restrict__ W5, float* __restrict__ c5acc) {
    int row = blockIdx.y;
    const float4* wr = (const float4*)(W5 + (size_t)row * C5_K);
    const float4* hv = (const float4*)h4;
    int i = blockIdx.x * C5_CHUNK_F4 + (int)threadIdx.x;
    float s0 = 0.f, s1 = 0.f;
    #pragma unroll
    for (int k = 0; k < 6; ++k) {
        float4 wa = nt_load4(&wr[i]);
        float4 wb = nt_load4(&wr[i + 256]);
        float4 ha = hv[i];
        float4 hb = hv[i + 256];
        s0 = fmaf(wa.x, ha.x, s0); s0 = fmaf(wa.y, ha.y, s0);
        s0 = fmaf(wa.z, ha.z, s0); s0 = fmaf(wa.w, ha.w, s0);
        s1 = fmaf(wb.x, hb.x, s1); s1 = fmaf(wb.y, hb.y, s1);
        s1 = fmaf(wb.z, hb.z, s1); s1 = fmaf(wb.w, hb.w, s1);
        i += 512;
    }
    if (threadIdx.x < 53) {   // i == chunk_start + 3072 + tid, valid for tid < 53
        float4 w = nt_load4(&wr[i]);
        float4 h = hv[i];
        s0 = fmaf(w.x, h.x, s0); s0 = fmaf(w.y, h.y, s0);
        s0 = fmaf(w.z, h.z, s0); s0 = fmaf(w.w, h.w, s0);
    }
    float s = block_reduce_256(s0 + s1);
    if (threadIdx.x == 0) atomicAdd(&c5acc[row], s);
}

// F6+F7 fused: each block stages a 96-row W6 panel (46.5 KB LDS, coalesced nt
// float4), computes h6[base..base+96) = relu(W6 @ relu(c5) + b6) into LDS,
// then contracts those 96 rows against the 54x96 W7 slice and atomically
// accumulates 54 partial outputs (out pre-seeded with b7 by c1 block 0).
// Kills the f7 launch and the h6 global round-trip.
__global__ __launch_bounds__(256) void f6f7_kernel(const float* __restrict__ c5acc,
        const float* __restrict__ W6, const float* __restrict__ b6,
        const float* __restrict__ W7, float* __restrict__ out) {
    __shared__ float ws6[F6_RPB * F6_STRIDE];  // 47616 B
    __shared__ float h5s[120];
    __shared__ float h6s[F6_RPB];
    __shared__ float part[3 * 54];
    int tid = threadIdx.x;
    int base = blockIdx.x * F6_RPB;
    if (tid < 120) h5s[tid] = fmaxf(c5acc[tid], 0.f);
    const float4* src = (const float4*)(W6 + (size_t)base * 120);
    #pragma unroll
    for (int it = 0; it < 12; ++it) {
        int f4 = tid + it * 256;               // 0..2879 (last iter: tid < 64)
        if (f4 < F6_PANEL_F4) {
            float4 v = nt_load4(&src[f4]);
            int flat = f4 * 4;
            int row = flat / 120;
            int col = flat - row * 120;        // multiple of 4
            *(float4*)&ws6[row * F6_STRIDE + col] = v;
        }
    }
    __syncthreads();
    if (tid < 2 * F6_RPB) {                    // 192 threads, 2 per row
        int row  = tid >> 1;
        int half = tid & 1;
        const float4* wr4 = (const float4*)&ws6[row * F6_STRIDE + half * 60];
        const float4* hh4 = (const float4*)&h5s[half * 60];
        float a = 0.f;
        #pragma unroll
        for (int j = 0; j < 15; ++j) {
            float4 w = wr4[j], h = hh4[j];
            a = fmaf(w.x, h.x, a); a = fmaf(w.y, h.y, a);
            a = fmaf(w.z, h.z, a); a = fmaf(w.w, h.w, a);
        }
        a += __shfl_xor(a, 1, 64);
        if (half == 0) h6s[row] = fmaxf(a + b6[base + row], 0.f);
    }
    __syncthreads();
    // F7 slice: thread (j, seg) does 32 MACs; W7 rows are contiguous so each
    // thread's 128 B run fully consumes its cache lines.
    if (tid < 162) {                           // 54 outputs x 3 segments of 32
        int j = tid % 54, seg = tid / 54;
        const float4* w7 = (const float4*)(W7 + (size_t)j * F6_OUT + base + seg * 32);
        const float* hh = &h6s[seg * 32];
        float p = 0.f;
        #pragma unroll
        for (int q = 0; q < 8; ++q) {
            float4 w = nt_load4(&w7[q]);
            p = fmaf(w.x, hh[4 * q + 0], p); p = fmaf(w.y, hh[4 * q + 1], p);
            p = fmaf(w.z, hh[4 * q + 2], p); p = fmaf(w.w, hh[4 * q + 3], p);
        }
        part[tid] = p;                         // part[seg*54 + j]
    }
    __syncthreads();
    if (tid < 54) {
        atomicAdd(&out[tid], part[tid] + part[54 + tid] + part[108 + tid]);
    }
}

extern "C" void kernel_launch(void* const* d_in, const int* in_sizes, int n_in,
                              void* d_out, int out_size, void* d_ws, size_t ws_size,
                              hipStream_t stream) {
    const float* x  = (const float*)d_in[0];
    const float* W1 = (const float*)d_in[1];
    const float* b1 = (const float*)d_in[2];
    const float* W3 = (const float*)d_in[3];
    const float* b3 = (const float*)d_in[4];
    const float* W5 = (const float*)d_in[5];
    const float* b5 = (const float*)d_in[6];
    const float* W6 = (const float*)d_in[7];
    const float* b6 = (const float*)d_in[8];
    const float* W7 = (const float*)d_in[9];
    const float* b7 = (const float*)d_in[10];
    float* out = (float*)d_out;
    float* ws  = (float*)d_ws;

    float* h2 = ws + WS_H2;
    float* h4 = ws + WS_H4;
    float* c5 = ws + WS_C5;

    {
        int total = 6 * P1 * P1;
        c1_s2_kernel<<<(total + 255) / 256, 256, 0, stream>>>(x, W1, b1, h2, b5, b7, c5, out);
    }
    {
        int total = 16 * P2 * P2;
        c3_s4_kernel<<<(total + 255) / 256, 256, 0, stream>>>(h2, W3, b3, h4);
    }
    c5_kernel<<<dim3(C5_K4 / C5_CHUNK_F4, 120), 256, 0, stream>>>(h4, W5, c5);
    f6f7_kernel<<<F6_NBLK, 256, 0, stream>>>(c5, W6, b6, W7, out);
}

// Round 2
// 272.821 us; speedup vs baseline: 1.0377x; 1.0377x over previous
//
#include <hip/hip_runtime.h>

typedef float f32x4 __attribute__((ext_vector_type(4)));

#define P1 254   // pooled size after C1+S2
#define P2 125   // pooled size after C3+S4
#define C5_K 250000           // 16*125*125
#define C5_K4 62500           // in float4
#define C5_CHUNK_F4 3125      // 20 chunks per row -> grid (20,120) = 2400 blocks
#define F6_OUT 98304

#define F6_RPB 96             // rows per panel
#define F6_STRIDE 124         // LDS row stride (pad +4 floats)
#define F6_NBLK 512           // 512 blocks x 2 panels = 1024 panels (exactly 2 blocks/CU)
#define F6_PANEL_F4 (F6_RPB * 120 / 4)  // 2880 float4 per W6 panel

// ---- ws layout (floats) ----
#define WS_H2 0        // 6*254*254 = 387096
#define WS_H4 400000   // 16*125*125 = 250000
#define WS_C5 650000   // 120

__device__ __forceinline__ float4 nt_load4(const float4* p) {
    f32x4 v = __builtin_nontemporal_load((const f32x4*)p);
    return make_float4(v.x, v.y, v.z, v.w);
}

// C1 conv 5x5 (1->6) + ReLU + 2x2 avgpool, fused. One thread per pooled output.
// Block 0 also seeds the c5 accumulator (b5) and the output accumulator (b7).
__global__ __launch_bounds__(256) void c1_s2_kernel(const float* __restrict__ x,
        const float* __restrict__ W1, const float* __restrict__ b1,
        float* __restrict__ h2,
        const float* __restrict__ b5, const float* __restrict__ b7,
        float* __restrict__ c5acc, float* __restrict__ out) {
    if (blockIdx.x == 0) {
        int t = threadIdx.x;
        if (t < 120) c5acc[t] = b5[t];
        if (t >= 128 && t < 182) out[t - 128] = b7[t - 128];
    }
    int t = blockIdx.x * 256 + threadIdx.x;
    const int total = 6 * P1 * P1;
    if (t >= total) return;
    int c  = t / (P1 * P1);
    int r  = t % (P1 * P1);
    int y  = r / P1, x0 = r % P1;

    float w[25];
    #pragma unroll
    for (int k = 0; k < 25; ++k) w[k] = W1[c * 25 + k];

    float p[6][6];
    const float2* xin2 = (const float2*)(x + (2 * y) * 512 + 2 * x0);  // 8B-aligned
    #pragma unroll
    for (int i = 0; i < 6; ++i) {
        float2 a0 = xin2[i * 256 + 0];
        float2 a1 = xin2[i * 256 + 1];
        float2 a2 = xin2[i * 256 + 2];
        p[i][0] = a0.x; p[i][1] = a0.y; p[i][2] = a1.x;
        p[i][3] = a1.y; p[i][4] = a2.x; p[i][5] = a2.y;
    }

    float bias = b1[c];
    float s = 0.f;
    #pragma unroll
    for (int dy = 0; dy < 2; ++dy)
        #pragma unroll
        for (int dx = 0; dx < 2; ++dx) {
            float a = bias;
            #pragma unroll
            for (int kh = 0; kh < 5; ++kh)
                #pragma unroll
                for (int kw = 0; kw < 5; ++kw)
                    a = fmaf(p[dy + kh][dx + kw], w[kh * 5 + kw], a);
            s += fmaxf(a, 0.f);
        }
    h2[t] = 0.25f * s;
}

// C3 sparse-connected conv 5x5 (6->16) + ReLU + 2x2 avgpool, fused.
__global__ __launch_bounds__(256) void c3_s4_kernel(const float* __restrict__ h2,
        const float* __restrict__ W3, const float* __restrict__ b3,
        float* __restrict__ h4) {
    const unsigned char MASK[16] = {7,14,28,56,49,35,15,30,60,57,51,39,27,54,45,63};
    int t = blockIdx.x * 256 + threadIdx.x;
    const int total = 16 * P2 * P2;
    if (t >= total) return;
    int o  = t / (P2 * P2);
    int r  = t % (P2 * P2);
    int y  = r / P2, x0 = r % P2;

    float a00, a01, a10, a11;
    a00 = a01 = a10 = a11 = b3[o];
    unsigned m = MASK[o];

    for (int i = 0; i < 6; ++i) {
        if (!((m >> i) & 1)) continue;
        const float2* hp2 = (const float2*)(h2 + i * P1 * P1 + (2 * y) * P1 + 2 * x0);
        const float* wp = W3 + (o * 6 + i) * 25;
        float w[25];
        #pragma unroll
        for (int k = 0; k < 25; ++k) w[k] = wp[k];
        float p[6][6];
        #pragma unroll
        for (int ii = 0; ii < 6; ++ii) {
            float2 a0 = hp2[ii * 127 + 0];
            float2 a1 = hp2[ii * 127 + 1];
            float2 a2 = hp2[ii * 127 + 2];
            p[ii][0] = a0.x; p[ii][1] = a0.y; p[ii][2] = a1.x;
            p[ii][3] = a1.y; p[ii][4] = a2.x; p[ii][5] = a2.y;
        }
        #pragma unroll
        for (int kh = 0; kh < 5; ++kh)
            #pragma unroll
            for (int kw = 0; kw < 5; ++kw) {
                float wv = w[kh * 5 + kw];
                a00 = fmaf(p[kh][kw],         wv, a00);
                a01 = fmaf(p[kh][kw + 1],     wv, a01);
                a10 = fmaf(p[kh + 1][kw],     wv, a10);
                a11 = fmaf(p[kh + 1][kw + 1], wv, a11);
            }
    }
    h4[t] = 0.25f * (fmaxf(a00, 0.f) + fmaxf(a01, 0.f) + fmaxf(a10, 0.f) + fmaxf(a11, 0.f));
}

__device__ __forceinline__ float block_reduce_256(float v) {
    #pragma unroll
    for (int off = 32; off > 0; off >>= 1) v += __shfl_down(v, off, 64);
    __shared__ float s[4];
    int lane = threadIdx.x & 63, wv = threadIdx.x >> 6;
    if (lane == 0) s[wv] = v;
    __syncthreads();
    return s[0] + s[1] + s[2] + s[3];
}

// C5: 120 dot-products of length 250000. Split-K, compile-time trip count:
// 3125 f4/chunk = 12*256 + 53 -> 6 unrolled x2 iterations + predicated tail.
// Dual accumulators + paired nt loads keep the 120 MB W5 stream deep in flight.
__global__ __launch_bounds__(256) void c5_kernel(const float* __restrict__ h4,
        const float* __restrict__ W5, float* __restrict__ c5acc) {
    int row = blockIdx.y;
    const float4* wr = (const float4*)(W5 + (size_t)row * C5_K);
    const float4* hv = (const float4*)h4;
    int i = blockIdx.x * C5_CHUNK_F4 + (int)threadIdx.x;
    float s0 = 0.f, s1 = 0.f;
    #pragma unroll
    for (int k = 0; k < 6; ++k) {
        float4 wa = nt_load4(&wr[i]);
        float4 wb = nt_load4(&wr[i + 256]);
        float4 ha = hv[i];
        float4 hb = hv[i + 256];
        s0 = fmaf(wa.x, ha.x, s0); s0 = fmaf(wa.y, ha.y, s0);
        s0 = fmaf(wa.z, ha.z, s0); s0 = fmaf(wa.w, ha.w, s0);
        s1 = fmaf(wb.x, hb.x, s1); s1 = fmaf(wb.y, hb.y, s1);
        s1 = fmaf(wb.z, hb.z, s1); s1 = fmaf(wb.w, hb.w, s1);
        i += 512;
    }
    if (threadIdx.x < 53) {   // i == chunk_start + 3072 + tid, valid for tid < 53
        float4 w = nt_load4(&wr[i]);
        float4 h = hv[i];
        s0 = fmaf(w.x, h.x, s0); s0 = fmaf(w.y, h.y, s0);
        s0 = fmaf(w.z, h.z, s0); s0 = fmaf(w.w, h.w, s0);
    }
    float s = block_reduce_256(s0 + s1);
    if (threadIdx.x == 0) atomicAdd(&c5acc[row], s);
}

// F6+F7 fused, 2 panels per block (512 blocks = exactly 2 resident blocks/CU).
// Per panel: stage 96-row W6 panel (46.5 KB LDS, coalesced nt float4),
// h6 = relu(W6 @ relu(c5) + b6) into LDS, then contract against the 54x96 W7
// slice (216 threads, 4 segments of 24 cols). out-contributions of both panels
// accumulate in registers -> ONE atomicAdd per output per block (27.6k total,
// half of round-1's 55k same-address atomics).
__global__ __launch_bounds__(256) void f6f7_kernel(const float* __restrict__ c5acc,
        const float* __restrict__ W6, const float* __restrict__ b6,
        const float* __restrict__ W7, float* __restrict__ out) {
    __shared__ __align__(16) float ws6[F6_RPB * F6_STRIDE];  // 47616 B
    __shared__ __align__(16) float h5s[120];
    __shared__ __align__(16) float h6s[F6_RPB];
    __shared__ float part[4 * 54];
    int tid = threadIdx.x;
    if (tid < 120) h5s[tid] = fmaxf(c5acc[tid], 0.f);
    float oacc = 0.f;   // tid<54: this block's contribution to out[tid]

    #pragma unroll 1
    for (int pp = 0; pp < 2; ++pp) {
        int base = (blockIdx.x + pp * F6_NBLK) * F6_RPB;
        const float4* src = (const float4*)(W6 + (size_t)base * 120);
        #pragma unroll
        for (int it = 0; it < 12; ++it) {
            int f4 = tid + it * 256;               // 0..2879 (last iter: tid < 64)
            if (f4 < F6_PANEL_F4) {
                float4 v = nt_load4(&src[f4]);
                int flat = f4 * 4;
                int row = flat / 120;
                int col = flat - row * 120;        // multiple of 4
                *(float4*)&ws6[row * F6_STRIDE + col] = v;
            }
        }
        __syncthreads();
        if (tid < 2 * F6_RPB) {                    // 192 threads, 2 per row
            int row  = tid >> 1;
            int half = tid & 1;
            const float4* wr4 = (const float4*)&ws6[row * F6_STRIDE + half * 60];
            const float4* hh4 = (const float4*)&h5s[half * 60];
            float a = 0.f;
            #pragma unroll
            for (int j = 0; j < 15; ++j) {
                float4 w = wr4[j], h = hh4[j];
                a = fmaf(w.x, h.x, a); a = fmaf(w.y, h.y, a);
                a = fmaf(w.z, h.z, a); a = fmaf(w.w, h.w, a);
            }
            a += __shfl_xor(a, 1, 64);
            if (half == 0) h6s[row] = fmaxf(a + b6[base + row], 0.f);
        }
        __syncthreads();
        // F7 slice: 216 threads, thread (j,seg) does 24 MACs from contiguous W7.
        if (tid < 216) {
            int j = tid % 54, seg = tid / 54;      // seg 0..3, 24 cols each
            const float4* w7 = (const float4*)(W7 + (size_t)j * F6_OUT + base + seg * 24);
            const float* hh = &h6s[seg * 24];
            float p = 0.f;
            #pragma unroll
            for (int q = 0; q < 6; ++q) {
                float4 w = nt_load4(&w7[q]);
                p = fmaf(w.x, hh[4 * q + 0], p); p = fmaf(w.y, hh[4 * q + 1], p);
                p = fmaf(w.z, hh[4 * q + 2], p); p = fmaf(w.w, hh[4 * q + 3], p);
            }
            part[seg * 54 + j] = p;
        }
        __syncthreads();
        if (tid < 54)
            oacc += part[tid] + part[54 + tid] + part[108 + tid] + part[162 + tid];
        __syncthreads();   // part[] fully read before next panel overwrites it
    }
    if (tid < 54) atomicAdd(&out[tid], oacc);
}

extern "C" void kernel_launch(void* const* d_in, const int* in_sizes, int n_in,
                              void* d_out, int out_size, void* d_ws, size_t ws_size,
                              hipStream_t stream) {
    const float* x  = (const float*)d_in[0];
    const float* W1 = (const float*)d_in[1];
    const float* b1 = (const float*)d_in[2];
    const float* W3 = (const float*)d_in[3];
    const float* b3 = (const float*)d_in[4];
    const float* W5 = (const float*)d_in[5];
    const float* b5 = (const float*)d_in[6];
    const float* W6 = (const float*)d_in[7];
    const float* b6 = (const float*)d_in[8];
    const float* W7 = (const float*)d_in[9];
    const float* b7 = (const float*)d_in[10];
    float* out = (float*)d_out;
    float* ws  = (float*)d_ws;

    float* h2 = ws + WS_H2;
    float* h4 = ws + WS_H4;
    float* c5 = ws + WS_C5;

    {
        int total = 6 * P1 * P1;
        c1_s2_kernel<<<(total + 255) / 256, 256, 0, stream>>>(x, W1, b1, h2, b5, b7, c5, out);
    }
    {
        int total = 16 * P2 * P2;
        c3_s4_kernel<<<(total + 255) / 256, 256, 0, stream>>>(h2, W3, b3, h4);
    }
    c5_kernel<<<dim3(C5_K4 / C5_CHUNK_F4, 120), 256, 0, stream>>>(h4, W5, c5);
    f6f7_kernel<<<F6_NBLK, 256, 0, stream>>>(c5, W6, b6, W7, out);
}